// Round 4
// baseline (285.174 us; speedup 1.0000x reference)
//
#include <hip/hip_runtime.h>

// DeformConv fused, NHWC-gather edition.
// B=4, C=128, H=W=96, O=128, 3x3 s1 p1 d1, G=1.
// Pipeline: prep (weights->bf16, K reordered) ; nhwc (x,x2 -> NHWC bf16) ;
//           fused (offset/mask MFMA conv -> bilinear params -> deform MFMA).
#define CIN   128
#define HH    96
#define WW    96
#define OUTC  128
#define HWSZ  9216
#define KK    9
#define KTOT  1152        // k' = tap*128 + c (tap-major)

typedef __bf16 bf16x8 __attribute__((ext_vector_type(8)));
typedef float  f32x4  __attribute__((ext_vector_type(4)));

__device__ __forceinline__ unsigned short f2bf(float f) {
  unsigned u = __builtin_bit_cast(unsigned, f);
  u += 0x7fffu + ((u >> 16) & 1u);               // RNE
  return (unsigned short)(u >> 16);
}
__device__ __forceinline__ float bf2f_lo(unsigned w) {
  unsigned u = w << 16;
  return __builtin_bit_cast(float, u);
}
__device__ __forceinline__ float bf2f_hi(unsigned w) {
  unsigned u = w & 0xffff0000u;
  return __builtin_bit_cast(float, u);
}
// pack two floats to bf16x2 (round-half-up) : 3 VALU
__device__ __forceinline__ unsigned pack_bf(float v0, float v1) {
  unsigned u0 = __builtin_bit_cast(unsigned, v0) + 0x8000u;
  unsigned u1 = __builtin_bit_cast(unsigned, v1) + 0x8000u;
  return __builtin_amdgcn_perm(u1, u0, 0x07060302u);   // {lo16=top(v0), hi16=top(v1)}
}

// ws layout (u16 offsets):
//   wtb   bf16[128][1152] @ 0         (k' = tap*128+c)
//   wt2b  bf16[32][1152]  @ 147456    (oc 0-17 offset, 18-26 mask, 27-31 zero)
//   bias32 f32[32]        @ 184320
//   xn    bf16[4][9216][128] @ 184384 (NHWC)
//   x2n   bf16[4][9216][128] @ 184384+4718592
#define WT2B_O 147456
#define BIAS_O 184320
#define XN_O   184384
#define X2N_O  (184384 + 4718592)
// total ws: ~19.3 MB

__global__ __launch_bounds__(256) void prep(
    const float* __restrict__ offw, const float* __restrict__ maskw,
    const float* __restrict__ defw, const float* __restrict__ offb,
    const float* __restrict__ maskb, void* __restrict__ wsv) {
  unsigned short* wtb  = (unsigned short*)wsv;
  unsigned short* wt2b = wtb + WT2B_O;
  float* bias32 = (float*)(wtb + BIAS_O);
  int idx = blockIdx.x * 256 + threadIdx.x;
  if (idx < OUTC * KTOT) {
    int o = idx / KTOT, r = idx - o * KTOT;
    int c = r / KK, tap = r - c * KK;
    wtb[o * KTOT + tap * 128 + c] = f2bf(defw[idx]);     // coalesced read
  } else if (idx < OUTC * KTOT + 32 * KTOT) {
    int j = idx - OUTC * KTOT;
    int oc = j / KTOT, r = j - oc * KTOT;
    int c = r / KK, tap = r - c * KK;
    float v = 0.f;
    if (oc < 18)      v = offw[j];
    else if (oc < 27) v = maskw[j - 18 * KTOT];
    wt2b[oc * KTOT + tap * 128 + c] = f2bf(v);
  } else if (idx < OUTC * KTOT + 32 * KTOT + 32) {
    int j = idx - OUTC * KTOT - 32 * KTOT;
    float v = 0.f;
    if (j < 18) v = offb[j]; else if (j < 27) v = maskb[j - 18];
    bias32[j] = v;
  }
}

// NCHW f32 -> NHWC bf16, LDS tile transpose. Block = 64 px x 128 c.
__global__ __launch_bounds__(256) void nhwc(
    const float* __restrict__ x, const float* __restrict__ x2,
    void* __restrict__ wsv) {
  __shared__ unsigned short tile[64][138];   // stride 138 u16: 69 dwords -> 2-way max
  int rb = blockIdx.x;
  int tsel = rb / 576;
  int rem = rb - tsel * 576;
  int b = rem / 144;
  int hw0 = (rem % 144) * 64;
  const float* src = tsel ? x2 : x;
  unsigned short* dst = (unsigned short*)wsv + (tsel ? X2N_O : XN_O);
  int t = threadIdx.x;
  int px = t & 63, cg = t >> 6;
#pragma unroll
  for (int q = 0; q < 16; ++q) {
    int c = cg * 32 + 2 * q;
    float f0 = src[((size_t)(b * CIN + c))     * HWSZ + hw0 + px];
    float f1 = src[((size_t)(b * CIN + c + 1)) * HWSZ + hw0 + px];
    *(unsigned*)&tile[px][c] = pack_bf(f0, f1);
  }
  __syncthreads();
  unsigned* drow = (unsigned*)(dst + ((size_t)(b * HWSZ + hw0)) * 128);
#pragma unroll
  for (int k = 0; k < 16; ++k) {
    int e = t + 256 * k;
    int pxx = e >> 6, j = e & 63;
    unsigned v = *(const unsigned*)&tile[pxx][2 * j];
    drow[(size_t)pxx * 64 + j] = v;
  }
}

// Fused: block = 64 px (one strip), wave w = m-tile w (16 px) x all 128 o.
// No LDS staging in the GEMMs: A-frags gathered straight from NHWC bf16,
// B-frags streamed from L2-resident transposed weights.
__global__ __launch_bounds__(256, 4) void fused(
    const float* __restrict__ defb, const void* __restrict__ wsv,
    float* __restrict__ out) {
  const unsigned short* wtb  = (const unsigned short*)wsv;
  const unsigned short* wt2b = wtb + WT2B_O;
  const float* bias32 = (const float*)(wtb + BIAS_O);
  const unsigned short* xn  = wtb + XN_O;
  const unsigned short* x2n = wtb + X2N_O;

  __shared__ float om[32][68];       // offsets/mask dump; reused as epilogue buf
  __shared__ uint4 prm[KK * 64];     // 4 u16 corner pos + 4 bf16 weights

  int t = threadIdx.x;
  int w = t >> 6;
  int l15 = t & 15, quad = (t >> 4) & 3;
  int px_m = w * 16 + l15;           // this thread's A row (pixel within strip)
  // XCD swizzle: 72 consecutive strips per XCD -> L2 residency
  int rb = blockIdx.x;
  int bid = (rb & 7) * 72 + (rb >> 3);
  int b = bid / 144;
  int pblk = (bid % 144) * 64;

  int gp = pblk + px_m;
  int ph = gp / WW, pw = gp % WW;

  // ===== phase 1: offset/mask GEMM (A direct from x2 NHWC) =====
  f32x4 oa0 = {0.f, 0.f, 0.f, 0.f};
  f32x4 oa1 = {0.f, 0.f, 0.f, 0.f};
  const unsigned short* x2nb = x2n + ((size_t)b * HWSZ) * 128;
  for (int tap = 0; tap < KK; ++tap) {
    int y = ph + tap / 3 - 1, xx = pw + tap % 3 - 1;
    bool ok = ((unsigned)y < HH) && ((unsigned)xx < WW);
    int pos = ok ? (y * WW + xx) : 0;
    const unsigned short* arow = x2nb + ((size_t)pos << 7);
#pragma unroll
    for (int ks = 0; ks < 4; ++ks) {
      int coff = ks * 32 + quad * 8;
      bf16x8 af = {};
      if (ok) af = *(const bf16x8*)(arow + coff);
      bf16x8 b0 = *(const bf16x8*)(wt2b + (size_t)l15 * KTOT + tap * 128 + coff);
      bf16x8 b1 = *(const bf16x8*)(wt2b + (size_t)(l15 + 16) * KTOT + tap * 128 + coff);
      oa0 = __builtin_amdgcn_mfma_f32_16x16x32_bf16(af, b0, oa0, 0, 0, 0);
      oa1 = __builtin_amdgcn_mfma_f32_16x16x32_bf16(af, b1, oa1, 0, 0, 0);
    }
  }
  // dump: C layout col=l15 (oc), row=quad*4+reg (px within m-tile)
#pragma unroll
  for (int nt = 0; nt < 2; ++nt) {
    f32x4 a = nt ? oa1 : oa0;
    int oc = nt * 16 + l15;
    float bia = bias32[oc];
#pragma unroll
    for (int r = 0; r < 4; ++r)
      om[oc][w * 16 + quad * 4 + r] = a[r] + bia;
  }
  __syncthreads();

  // ===== phase 2: bilinear params =====
  for (int e = t; e < KK * 64; e += 256) {
    int tap = e >> 6, pp = e & 63;
    int gp2 = pblk + pp;
    int h = gp2 / WW, ww_ = gp2 % WW;
    float dy = om[2 * tap][pp], dx = om[2 * tap + 1][pp];
    float mr = om[18 + tap][pp];
    float m = 1.f / (1.f + __expf(-mr));
    float py  = (float)(h + tap / 3 - 1) + dy;
    float pxx = (float)(ww_ + tap % 3 - 1) + dx;
    float y0f = floorf(py), x0f = floorf(pxx);
    int y0 = (int)y0f, x0 = (int)x0f;
    float ly = py - y0f, lx = pxx - x0f;
    int y1 = y0 + 1, x1 = x0 + 1;
    bool vy0 = (unsigned)y0 < HH, vy1 = (unsigned)y1 < HH;
    bool vx0 = (unsigned)x0 < WW, vx1 = (unsigned)x1 < WW;
    int cy0 = min(max(y0, 0), HH - 1), cy1 = min(max(y1, 0), HH - 1);
    int cx0 = min(max(x0, 0), WW - 1), cx1 = min(max(x1, 0), WW - 1);
    unsigned i00 = cy0 * WW + cx0, i01 = cy0 * WW + cx1;
    unsigned i10 = cy1 * WW + cx0, i11 = cy1 * WW + cx1;
    float w00 = (vy0 && vx0) ? m * (1.f - ly) * (1.f - lx) : 0.f;
    float w01 = (vy0 && vx1) ? m * (1.f - ly) * lx         : 0.f;
    float w10 = (vy1 && vx0) ? m * ly * (1.f - lx)         : 0.f;
    float w11 = (vy1 && vx1) ? m * ly * lx                 : 0.f;
    uint4 pk;
    pk.x = i00 | (i01 << 16);
    pk.y = i10 | (i11 << 16);
    pk.z = (unsigned)f2bf(w00) | ((unsigned)f2bf(w01) << 16);
    pk.w = (unsigned)f2bf(w10) | ((unsigned)f2bf(w11) << 16);
    prm[e] = pk;
  }
  __syncthreads();

  // ===== phase 3: deformable GEMM, no LDS, no barriers =====
  f32x4 acc[8];
#pragma unroll
  for (int nt = 0; nt < 8; ++nt) acc[nt] = (f32x4){0.f, 0.f, 0.f, 0.f};
  const unsigned short* xnb = xn + ((size_t)b * HWSZ) * 128;

  for (int tap = 0; tap < KK; ++tap) {
    uint4 pk = prm[tap * 64 + px_m];
    const unsigned short* r00 = xnb + ((size_t)(pk.x & 0xffffu) << 7);
    const unsigned short* r01 = xnb + ((size_t)(pk.x >> 16) << 7);
    const unsigned short* r10 = xnb + ((size_t)(pk.y & 0xffffu) << 7);
    const unsigned short* r11 = xnb + ((size_t)(pk.y >> 16) << 7);
    float w00 = bf2f_lo(pk.z), w01 = bf2f_hi(pk.z);
    float w10 = bf2f_lo(pk.w), w11 = bf2f_hi(pk.w);
#pragma unroll
    for (int ks = 0; ks < 4; ++ks) {
      int coff = ks * 32 + quad * 8;
      uint4 c00 = *(const uint4*)(r00 + coff);
      uint4 c01 = *(const uint4*)(r01 + coff);
      uint4 c10 = *(const uint4*)(r10 + coff);
      uint4 c11 = *(const uint4*)(r11 + coff);
      const unsigned* a00 = (const unsigned*)&c00;
      const unsigned* a01 = (const unsigned*)&c01;
      const unsigned* a10 = (const unsigned*)&c10;
      const unsigned* a11 = (const unsigned*)&c11;
      unsigned od[4];
#pragma unroll
      for (int j = 0; j < 4; ++j) {
        float lo = w00 * bf2f_lo(a00[j]) + w01 * bf2f_lo(a01[j])
                 + w10 * bf2f_lo(a10[j]) + w11 * bf2f_lo(a11[j]);
        float hi = w00 * bf2f_hi(a00[j]) + w01 * bf2f_hi(a01[j])
                 + w10 * bf2f_hi(a10[j]) + w11 * bf2f_hi(a11[j]);
        od[j] = pack_bf(lo, hi);
      }
      bf16x8 af = __builtin_bit_cast(bf16x8, make_uint4(od[0], od[1], od[2], od[3]));
      const unsigned short* wr = wtb + tap * 128 + coff + (size_t)l15 * KTOT;
#pragma unroll
      for (int nt = 0; nt < 8; ++nt) {
        bf16x8 bb = *(const bf16x8*)(wr + (size_t)(nt * 16) * KTOT);
        acc[nt] = __builtin_amdgcn_mfma_f32_16x16x32_bf16(af, bb, acc[nt], 0, 0, 0);
      }
    }
  }

  // ===== phase 4: epilogue (bias + LDS transpose, coalesced stores) =====
  for (int r = 0; r < 4; ++r) {
    f32x4 a0 = acc[2 * r], a1 = acc[2 * r + 1];
    float db0 = defb[r * 32 + l15];
    float db1 = defb[r * 32 + 16 + l15];
#pragma unroll
    for (int reg = 0; reg < 4; ++reg) {
      om[l15]     [w * 16 + quad * 4 + reg] = a0[reg] + db0;
      om[16 + l15][w * 16 + quad * 4 + reg] = a1[reg] + db1;
    }
    __syncthreads();
    int row = t >> 4;               // 0..15
    int col4 = (t & 15) * 4;
#pragma unroll
    for (int hrow = 0; hrow < 2; ++hrow) {
      int rr = row + hrow * 16;
      float4 v = *(float4*)&om[rr][col4];
      *(float4*)&out[((size_t)b * OUTC + r * 32 + rr) * HWSZ + pblk + col4] = v;
    }
    __syncthreads();
  }
}

extern "C" void kernel_launch(void* const* d_in, const int* in_sizes, int n_in,
                              void* d_out, int out_size, void* d_ws, size_t ws_size,
                              hipStream_t stream) {
  const float* x     = (const float*)d_in[0];
  const float* x2    = (const float*)d_in[1];
  const float* offw  = (const float*)d_in[2];
  const float* offb  = (const float*)d_in[3];
  const float* maskw = (const float*)d_in[4];
  const float* maskb = (const float*)d_in[5];
  const float* defw  = (const float*)d_in[6];
  const float* defb  = (const float*)d_in[7];
  float* out = (float*)d_out;

  // NHWC transpose: 2 tensors x 4 imgs x 144 strips
  hipLaunchKernelGGL(nhwc, dim3(1152), dim3(256), 0, stream, x, x2, d_ws);
  // weights: 147456 + 36864 + 32 elems -> 721 blocks
  hipLaunchKernelGGL(prep, dim3(721), dim3(256), 0, stream,
                     offw, maskw, defw, offb, maskb, d_ws);
  // fused: 576 strips (8 XCDs x 72)
  hipLaunchKernelGGL(fused, dim3(576), dim3(256), 0, stream, defb, d_ws, out);
}

// Round 5
// 193.388 us; speedup vs baseline: 1.4746x; 1.4746x over previous
//
#include <hip/hip_runtime.h>

// DeformConv fused, NHWC-gather + LDS-staged-B edition.
// B=4, C=128, H=W=96, O=128, 3x3 s1 p1 d1, G=1.
#define CIN   128
#define HH    96
#define WW    96
#define OUTC  128
#define HWSZ  9216
#define KK    9
#define KTOT  1152        // k' = tap*128 + c (tap-major)

typedef __bf16 bf16x8 __attribute__((ext_vector_type(8)));
typedef float  f32x4  __attribute__((ext_vector_type(4)));

__device__ __forceinline__ unsigned short f2bf(float f) {
  unsigned u = __builtin_bit_cast(unsigned, f);
  u += 0x7fffu + ((u >> 16) & 1u);               // RNE
  return (unsigned short)(u >> 16);
}
__device__ __forceinline__ float bf2f_lo(unsigned w) {
  unsigned u = w << 16;
  return __builtin_bit_cast(float, u);
}
__device__ __forceinline__ float bf2f_hi(unsigned w) {
  unsigned u = w & 0xffff0000u;
  return __builtin_bit_cast(float, u);
}
// pack two floats to bf16x2 (round-half-up) : 3 VALU
__device__ __forceinline__ unsigned pack_bf(float v0, float v1) {
  unsigned u0 = __builtin_bit_cast(unsigned, v0) + 0x8000u;
  unsigned u1 = __builtin_bit_cast(unsigned, v1) + 0x8000u;
  return __builtin_amdgcn_perm(u1, u0, 0x07060302u);
}

// ws layout (u16 offsets):
//   wtb   bf16[128][1152] @ 0         (k' = tap*128+c)
//   wt2b  bf16[32][1152]  @ 147456    (oc 0-17 offset, 18-26 mask, 27-31 zero)
//   bias32 f32[32]        @ 184320
//   xn    bf16[4][9216][128] @ 184384 (NHWC)
//   x2n   bf16[4][9216][128] @ 184384+4718592
#define WT2B_O 147456
#define BIAS_O 184320
#define XN_O   184384
#define X2N_O  (184384 + 4718592)

// Combined prep: blocks [0,1152) = NCHW->NHWC bf16 transpose of x/x2;
//                blocks [1152,1873) = weight reorder/cast.
__global__ __launch_bounds__(256) void prep_all(
    const float* __restrict__ x, const float* __restrict__ x2,
    const float* __restrict__ offw, const float* __restrict__ maskw,
    const float* __restrict__ defw, const float* __restrict__ offb,
    const float* __restrict__ maskb, void* __restrict__ wsv) {
  int bid = blockIdx.x;
  int t = threadIdx.x;
  if (bid < 1152) {
    __shared__ unsigned short tile[64][138];
    int tsel = bid / 576;
    int rem = bid - tsel * 576;
    int b = rem / 144;
    int hw0 = (rem % 144) * 64;
    const float* src = tsel ? x2 : x;
    unsigned short* dst = (unsigned short*)wsv + (tsel ? X2N_O : XN_O);
    int px = t & 63, cg = t >> 6;
#pragma unroll
    for (int q = 0; q < 16; ++q) {
      int c = cg * 32 + 2 * q;
      float f0 = src[((size_t)(b * CIN + c))     * HWSZ + hw0 + px];
      float f1 = src[((size_t)(b * CIN + c + 1)) * HWSZ + hw0 + px];
      *(unsigned*)&tile[px][c] = pack_bf(f0, f1);
    }
    __syncthreads();
    unsigned* drow = (unsigned*)(dst + ((size_t)(b * HWSZ + hw0)) * 128);
#pragma unroll
    for (int k = 0; k < 16; ++k) {
      int e = t + 256 * k;
      int pxx = e >> 6, j = e & 63;
      unsigned v = *(const unsigned*)&tile[pxx][2 * j];
      drow[(size_t)pxx * 64 + j] = v;
    }
    return;
  }
  unsigned short* wtb  = (unsigned short*)wsv;
  unsigned short* wt2b = wtb + WT2B_O;
  float* bias32 = (float*)(wtb + BIAS_O);
  int idx = (bid - 1152) * 256 + t;
  if (idx < OUTC * KTOT) {
    int o = idx / KTOT, r = idx - o * KTOT;
    int c = r / KK, tap = r - c * KK;
    wtb[o * KTOT + tap * 128 + c] = f2bf(defw[idx]);
  } else if (idx < OUTC * KTOT + 32 * KTOT) {
    int j = idx - OUTC * KTOT;
    int oc = j / KTOT, r = j - oc * KTOT;
    int c = r / KK, tap = r - c * KK;
    float v = 0.f;
    if (oc < 18)      v = offw[j];
    else if (oc < 27) v = maskw[j - 18 * KTOT];
    wt2b[oc * KTOT + tap * 128 + c] = f2bf(v);
  } else if (idx < OUTC * KTOT + 32 * KTOT + 32) {
    int j = idx - OUTC * KTOT - 32 * KTOT;
    float v = 0.f;
    if (j < 18) v = offb[j]; else if (j < 27) v = maskb[j - 18];
    bias32[j] = v;
  }
}

// Fused kernel. Block = 64-px strip; wave w = m-tile w (16 px) x all 128 o.
// Per tap: corner loads (global) hoisted; B tap-slice staged to LDS
// (coalesced); B-frags via ds_read_b128 (stride 68 dw = 8-clk floor).
__global__ __launch_bounds__(256, 3) void fused(
    const float* __restrict__ defb, const void* __restrict__ wsv,
    float* __restrict__ out) {
  const unsigned short* wtb  = (const unsigned short*)wsv;
  const unsigned short* wt2b = wtb + WT2B_O;
  const float* bias32 = (const float*)(wtb + BIAS_O);
  const unsigned short* xn  = wtb + XN_O;
  const unsigned short* x2n = wtb + X2N_O;

  __shared__ unsigned bw[128 * 68];   // 34.8 KB: B tile, bf16x2/dword, stride 68 dw
  __shared__ float om[32][68];        // 8.7 KB
  __shared__ uint4 prm[KK * 64];      // 9.2 KB   (total 52.7 KB -> 3 blocks/CU)

  int t = threadIdx.x;
  int w = t >> 6;
  int l15 = t & 15, quad = (t >> 4) & 3;
  int px_m = w * 16 + l15;
  int rb = blockIdx.x;
  int bid = (rb & 7) * 72 + (rb >> 3);   // XCD swizzle: 72 contiguous strips/XCD
  int b = bid / 144;
  int pblk = (bid % 144) * 64;
  int gp = pblk + px_m;
  int ph = gp / WW, pw = gp % WW;

  // ===== phase 1: offset/mask GEMM (A direct from x2 NHWC, B via LDS) =====
  f32x4 oa0 = {0.f, 0.f, 0.f, 0.f};
  f32x4 oa1 = {0.f, 0.f, 0.f, 0.f};
  const unsigned short* x2nb = x2n + ((size_t)b * HWSZ) * 128;
  for (int tap = 0; tap < KK; ++tap) {
    int y = ph + tap / 3 - 1, xx = pw + tap % 3 - 1;
    bool ok = ((unsigned)y < HH) && ((unsigned)xx < WW);
    int pos = ok ? (y * WW + xx) : 0;
    const unsigned short* arow = x2nb + ((size_t)pos << 7);
    uint4 a[4];
#pragma unroll
    for (int ks = 0; ks < 4; ++ks)
      a[ks] = ok ? *(const uint4*)(arow + ks * 32 + quad * 8)
                 : make_uint4(0u, 0u, 0u, 0u);
    __syncthreads();                       // prior tap's bw reads done
#pragma unroll
    for (int j = 0; j < 2; ++j) {          // stage 32 rows x 64 dw (8 KB)
      int cc = t + 256 * j;
      int row = cc >> 4, c16 = cc & 15;
      uint4 v = *(const uint4*)(wt2b + (size_t)row * KTOT + tap * 128 + c16 * 8);
      *(uint4*)&bw[row * 68 + c16 * 4] = v;
    }
    __syncthreads();
#pragma unroll
    for (int ks = 0; ks < 4; ++ks) {
      bf16x8 af = __builtin_bit_cast(bf16x8, a[ks]);
      bf16x8 b0 = *(const bf16x8*)&bw[(size_t)l15 * 68 + ks * 16 + quad * 4];
      bf16x8 b1 = *(const bf16x8*)&bw[(size_t)(l15 + 16) * 68 + ks * 16 + quad * 4];
      oa0 = __builtin_amdgcn_mfma_f32_16x16x32_bf16(af, b0, oa0, 0, 0, 0);
      oa1 = __builtin_amdgcn_mfma_f32_16x16x32_bf16(af, b1, oa1, 0, 0, 0);
    }
  }
  __syncthreads();
  // dump om (+bias): C layout col=l15 (oc), row=quad*4+reg (px in m-tile)
#pragma unroll
  for (int nt = 0; nt < 2; ++nt) {
    f32x4 a = nt ? oa1 : oa0;
    int oc = nt * 16 + l15;
    float bia = bias32[oc];
#pragma unroll
    for (int r = 0; r < 4; ++r)
      om[oc][w * 16 + quad * 4 + r] = a[r] + bia;
  }
  __syncthreads();

  // ===== phase 2: bilinear params =====
  for (int e = t; e < KK * 64; e += 256) {
    int tap = e >> 6, pp = e & 63;
    int gp2 = pblk + pp;
    int h = gp2 / WW, ww_ = gp2 % WW;
    float dy = om[2 * tap][pp], dx = om[2 * tap + 1][pp];
    float mr = om[18 + tap][pp];
    float m = 1.f / (1.f + __expf(-mr));
    float py  = (float)(h + tap / 3 - 1) + dy;
    float pxx = (float)(ww_ + tap % 3 - 1) + dx;
    float y0f = floorf(py), x0f = floorf(pxx);
    int y0 = (int)y0f, x0 = (int)x0f;
    float ly = py - y0f, lx = pxx - x0f;
    int y1 = y0 + 1, x1 = x0 + 1;
    bool vy0 = (unsigned)y0 < HH, vy1 = (unsigned)y1 < HH;
    bool vx0 = (unsigned)x0 < WW, vx1 = (unsigned)x1 < WW;
    int cy0 = min(max(y0, 0), HH - 1), cy1 = min(max(y1, 0), HH - 1);
    int cx0 = min(max(x0, 0), WW - 1), cx1 = min(max(x1, 0), WW - 1);
    unsigned i00 = cy0 * WW + cx0, i01 = cy0 * WW + cx1;
    unsigned i10 = cy1 * WW + cx0, i11 = cy1 * WW + cx1;
    float w00 = (vy0 && vx0) ? m * (1.f - ly) * (1.f - lx) : 0.f;
    float w01 = (vy0 && vx1) ? m * (1.f - ly) * lx         : 0.f;
    float w10 = (vy1 && vx0) ? m * ly * (1.f - lx)         : 0.f;
    float w11 = (vy1 && vx1) ? m * ly * lx                 : 0.f;
    uint4 pk;
    pk.x = i00 | (i01 << 16);
    pk.y = i10 | (i11 << 16);
    pk.z = (unsigned)f2bf(w00) | ((unsigned)f2bf(w01) << 16);
    pk.w = (unsigned)f2bf(w10) | ((unsigned)f2bf(w11) << 16);
    prm[e] = pk;
  }
  __syncthreads();

  // ===== phase 3: deformable GEMM (A gathered, B via LDS) =====
  f32x4 acc[8];
#pragma unroll
  for (int nt = 0; nt < 8; ++nt) acc[nt] = (f32x4){0.f, 0.f, 0.f, 0.f};
  const unsigned short* xnb = xn + ((size_t)b * HWSZ) * 128;

  for (int tap = 0; tap < KK; ++tap) {
    uint4 pk = prm[tap * 64 + px_m];
    const unsigned short* r00 = xnb + ((size_t)(pk.x & 0xffffu) << 7);
    const unsigned short* r01 = xnb + ((size_t)(pk.x >> 16) << 7);
    const unsigned short* r10 = xnb + ((size_t)(pk.y & 0xffffu) << 7);
    const unsigned short* r11 = xnb + ((size_t)(pk.y >> 16) << 7);
    float w00 = bf2f_lo(pk.z), w01 = bf2f_hi(pk.z);
    float w10 = bf2f_lo(pk.w), w11 = bf2f_hi(pk.w);
    // corner loads for all 4 ks hoisted (independent of LDS)
    uint4 c00[4], c01[4], c10[4], c11[4];
#pragma unroll
    for (int ks = 0; ks < 4; ++ks) {
      int coff = ks * 32 + quad * 8;
      c00[ks] = *(const uint4*)(r00 + coff);
      c01[ks] = *(const uint4*)(r01 + coff);
      c10[ks] = *(const uint4*)(r10 + coff);
      c11[ks] = *(const uint4*)(r11 + coff);
    }
    __syncthreads();                       // prior tap's bw reads done
#pragma unroll
    for (int j = 0; j < 8; ++j) {          // stage 128 rows x 64 dw (32 KB)
      int cc = t + 256 * j;
      int row = cc >> 4, c16 = cc & 15;
      uint4 v = *(const uint4*)(wtb + (size_t)row * KTOT + tap * 128 + c16 * 8);
      *(uint4*)&bw[row * 68 + c16 * 4] = v;
    }
    __syncthreads();
#pragma unroll
    for (int ks = 0; ks < 4; ++ks) {
      const unsigned* a00 = (const unsigned*)&c00[ks];
      const unsigned* a01 = (const unsigned*)&c01[ks];
      const unsigned* a10 = (const unsigned*)&c10[ks];
      const unsigned* a11 = (const unsigned*)&c11[ks];
      unsigned od[4];
#pragma unroll
      for (int j = 0; j < 4; ++j) {
        float lo = w00 * bf2f_lo(a00[j]) + w01 * bf2f_lo(a01[j])
                 + w10 * bf2f_lo(a10[j]) + w11 * bf2f_lo(a11[j]);
        float hi = w00 * bf2f_hi(a00[j]) + w01 * bf2f_hi(a01[j])
                 + w10 * bf2f_hi(a10[j]) + w11 * bf2f_hi(a11[j]);
        od[j] = pack_bf(lo, hi);
      }
      bf16x8 af = __builtin_bit_cast(bf16x8, make_uint4(od[0], od[1], od[2], od[3]));
#pragma unroll
      for (int nt = 0; nt < 8; ++nt) {
        bf16x8 bb = *(const bf16x8*)&bw[(size_t)(nt * 16 + l15) * 68 + ks * 16 + quad * 4];
        acc[nt] = __builtin_amdgcn_mfma_f32_16x16x32_bf16(af, bb, acc[nt], 0, 0, 0);
      }
    }
  }

  // ===== phase 4: epilogue (bias + LDS transpose, coalesced stores) =====
  for (int r = 0; r < 4; ++r) {
    f32x4 a0 = acc[2 * r], a1 = acc[2 * r + 1];
    float db0 = defb[r * 32 + l15];
    float db1 = defb[r * 32 + 16 + l15];
    if (r) __syncthreads();
#pragma unroll
    for (int reg = 0; reg < 4; ++reg) {
      om[l15]     [w * 16 + quad * 4 + reg] = a0[reg] + db0;
      om[16 + l15][w * 16 + quad * 4 + reg] = a1[reg] + db1;
    }
    __syncthreads();
    int row = t >> 4;
    int col4 = (t & 15) * 4;
#pragma unroll
    for (int hrow = 0; hrow < 2; ++hrow) {
      int rr = row + hrow * 16;
      float4 v = *(float4*)&om[rr][col4];
      *(float4*)&out[((size_t)b * OUTC + r * 32 + rr) * HWSZ + pblk + col4] = v;
    }
  }
}

extern "C" void kernel_launch(void* const* d_in, const int* in_sizes, int n_in,
                              void* d_out, int out_size, void* d_ws, size_t ws_size,
                              hipStream_t stream) {
  const float* x     = (const float*)d_in[0];
  const float* x2    = (const float*)d_in[1];
  const float* offw  = (const float*)d_in[2];
  const float* offb  = (const float*)d_in[3];
  const float* maskw = (const float*)d_in[4];
  const float* maskb = (const float*)d_in[5];
  const float* defw  = (const float*)d_in[6];
  const float* defb  = (const float*)d_in[7];
  float* out = (float*)d_out;

  // prep_all: 1152 transpose blocks + 721 weight blocks
  hipLaunchKernelGGL(prep_all, dim3(1873), dim3(256), 0, stream,
                     x, x2, offw, maskw, defw, offb, maskb, d_ws);
  // fused: 576 strips (8 XCDs x 72)
  hipLaunchKernelGGL(fused, dim3(576), dim3(256), 0, stream, defb, d_ws, out);
}

// Round 6
// 145.498 us; speedup vs baseline: 1.9600x; 1.3291x over previous
//
#include <hip/hip_runtime.h>

// DeformConv fused, row-coalesced-gather edition.
// B=4, C=128, H=W=96, O=128, 3x3 s1 p1 d1, G=1.
#define CIN   128
#define HH    96
#define WW    96
#define OUTC  128
#define HWSZ  9216
#define KK    9
#define KTOT  1152        // k' = tap*128 + c (tap-major)

typedef __bf16 bf16x8 __attribute__((ext_vector_type(8)));
typedef float  f32x4  __attribute__((ext_vector_type(4)));

__device__ __forceinline__ unsigned short f2bf(float f) {
  unsigned u = __builtin_bit_cast(unsigned, f);
  u += 0x7fffu + ((u >> 16) & 1u);               // RNE
  return (unsigned short)(u >> 16);
}
__device__ __forceinline__ float bf2f_lo(unsigned w) {
  unsigned u = w << 16;
  return __builtin_bit_cast(float, u);
}
__device__ __forceinline__ float bf2f_hi(unsigned w) {
  unsigned u = w & 0xffff0000u;
  return __builtin_bit_cast(float, u);
}
// pack two floats to bf16x2 (round-half-up) : 3 VALU
__device__ __forceinline__ unsigned pack_bf(float v0, float v1) {
  unsigned u0 = __builtin_bit_cast(unsigned, v0) + 0x8000u;
  unsigned u1 = __builtin_bit_cast(unsigned, v1) + 0x8000u;
  return __builtin_amdgcn_perm(u1, u0, 0x07060302u);
}

// ws layout (u16 offsets):
//   wtb   bf16[128][1152] @ 0         (k' = tap*128+c)
//   wt2b  bf16[32][1152]  @ 147456    (oc 0-17 offset, 18-26 mask, 27-31 zero)
//   bias32 f32[32]        @ 184320
//   xn    bf16[4][9216][128] @ 184384 (NHWC)
//   x2n   bf16[4][9216][128] @ 184384+4718592
#define WT2B_O 147456
#define BIAS_O 184320
#define XN_O   184384
#define X2N_O  (184384 + 4718592)

// Combined prep: blocks [0,1152) = NCHW->NHWC bf16 transpose of x/x2;
//                blocks [1152,1873) = weight reorder/cast.
__global__ __launch_bounds__(256) void prep_all(
    const float* __restrict__ x, const float* __restrict__ x2,
    const float* __restrict__ offw, const float* __restrict__ maskw,
    const float* __restrict__ defw, const float* __restrict__ offb,
    const float* __restrict__ maskb, void* __restrict__ wsv) {
  int bid = blockIdx.x;
  int t = threadIdx.x;
  if (bid < 1152) {
    __shared__ unsigned short tile[64][138];
    int tsel = bid / 576;
    int rem = bid - tsel * 576;
    int b = rem / 144;
    int hw0 = (rem % 144) * 64;
    const float* src = tsel ? x2 : x;
    unsigned short* dst = (unsigned short*)wsv + (tsel ? X2N_O : XN_O);
    int px = t & 63, cg = t >> 6;
#pragma unroll
    for (int q = 0; q < 16; ++q) {
      int c = cg * 32 + 2 * q;
      float f0 = src[((size_t)(b * CIN + c))     * HWSZ + hw0 + px];
      float f1 = src[((size_t)(b * CIN + c + 1)) * HWSZ + hw0 + px];
      *(unsigned*)&tile[px][c] = pack_bf(f0, f1);
    }
    __syncthreads();
    unsigned* drow = (unsigned*)(dst + ((size_t)(b * HWSZ + hw0)) * 128);
#pragma unroll
    for (int k = 0; k < 16; ++k) {
      int e = t + 256 * k;
      int pxx = e >> 6, j = e & 63;
      unsigned v = *(const unsigned*)&tile[pxx][2 * j];
      drow[(size_t)pxx * 64 + j] = v;
    }
    return;
  }
  unsigned short* wtb  = (unsigned short*)wsv;
  unsigned short* wt2b = wtb + WT2B_O;
  float* bias32 = (float*)(wtb + BIAS_O);
  int idx = (bid - 1152) * 256 + t;
  if (idx < OUTC * KTOT) {
    int o = idx / KTOT, r = idx - o * KTOT;
    int c = r / KK, tap = r - c * KK;
    wtb[o * KTOT + tap * 128 + c] = f2bf(defw[idx]);
  } else if (idx < OUTC * KTOT + 32 * KTOT) {
    int j = idx - OUTC * KTOT;
    int oc = j / KTOT, r = j - oc * KTOT;
    int c = r / KK, tap = r - c * KK;
    float v = 0.f;
    if (oc < 18)      v = offw[j];
    else if (oc < 27) v = maskw[j - 18 * KTOT];
    wt2b[oc * KTOT + tap * 128 + c] = f2bf(v);
  } else if (idx < OUTC * KTOT + 32 * KTOT + 32) {
    int j = idx - OUTC * KTOT - 32 * KTOT;
    float v = 0.f;
    if (j < 18) v = offb[j]; else if (j < 27) v = maskb[j - 18];
    bias32[j] = v;
  }
}

// Fused: block = 64-px strip; wave w = m-tile w (16 px) x all 128 o.
// Gather lanes remapped: (quad = px-in-group, l15 = channel octet) so each
// global instr reads 4 FULL 256B corner rows (4 segments, not 16).
// Corners combined in-lane, round-tripped through wave-private LDS `val`.
// B staged per tap in two 64-row halves (bw 17.4 KB).
__global__ __launch_bounds__(256, 3) void fused(
    const float* __restrict__ defb, const void* __restrict__ wsv,
    float* __restrict__ out) {
  const unsigned short* wtb  = (const unsigned short*)wsv;
  const unsigned short* wt2b = wtb + WT2B_O;
  const float* bias32 = (const float*)(wtb + BIAS_O);
  const unsigned short* xn  = wtb + XN_O;
  const unsigned short* x2n = wtb + X2N_O;

  __shared__ unsigned bw[64 * 68];         // 17.4 KB: B half-tile (64 o rows)
  __shared__ unsigned short val[64][136];  // 17.4 KB: A tile (bf16), pad 136
  __shared__ float om[32][68];             // 8.7 KB
  __shared__ unsigned sidxw[KK * 4 * 64];  // 9.2 KB: [(tap*4+cr)*64+px] idx|w<<16

  int t = threadIdx.x;
  int w = t >> 6;
  int l15 = t & 15, quad = (t >> 4) & 3;
  int rb = blockIdx.x;
  int bid = (rb & 7) * 72 + (rb >> 3);     // XCD swizzle
  int b = bid / 144;
  int pblk = (bid % 144) * 64;

  // gather-role pixels: px = 16w + G*4 + quad
  int phg[4], pwg[4];
#pragma unroll
  for (int G = 0; G < 4; ++G) {
    int p = pblk + w * 16 + G * 4 + quad;
    phg[G] = p / WW;
    pwg[G] = p - phg[G] * WW;
  }

  // ===== phase 1: offset/mask GEMM =====
  f32x4 oa0 = {0.f, 0.f, 0.f, 0.f};
  f32x4 oa1 = {0.f, 0.f, 0.f, 0.f};
  const unsigned short* x2nb = x2n + ((size_t)b * HWSZ) * 128;
  for (int tap = 0; tap < KK; ++tap) {
    int ky = tap / 3 - 1, kx = tap % 3 - 1;
    uint4 vG[4];
#pragma unroll
    for (int G = 0; G < 4; ++G) {
      int y = phg[G] + ky, xx = pwg[G] + kx;
      bool ok = ((unsigned)y < HH) && ((unsigned)xx < WW);
      int pos = ok ? (y * WW + xx) : 0;
      uint4 v = *(const uint4*)(x2nb + ((size_t)pos << 7) + l15 * 8);
      vG[G] = ok ? v : make_uint4(0u, 0u, 0u, 0u);
    }
#pragma unroll
    for (int j = 0; j < 2; ++j) {          // stage 32 oc rows x 64 dw
      int cc = t + 256 * j;
      int row = cc >> 4, c16 = cc & 15;
      *(uint4*)&bw[row * 68 + c16 * 4] =
          *(const uint4*)(wt2b + (size_t)row * KTOT + tap * 128 + c16 * 8);
    }
#pragma unroll
    for (int G = 0; G < 4; ++G)
      *(uint4*)&val[w * 16 + G * 4 + quad][l15 * 8] = vG[G];
    __syncthreads();
#pragma unroll
    for (int ks = 0; ks < 4; ++ks) {
      bf16x8 af = *(const bf16x8*)&val[w * 16 + l15][ks * 32 + quad * 8];
      bf16x8 b0 = *(const bf16x8*)&bw[(size_t)l15 * 68 + ks * 16 + quad * 4];
      bf16x8 b1 = *(const bf16x8*)&bw[(size_t)(l15 + 16) * 68 + ks * 16 + quad * 4];
      oa0 = __builtin_amdgcn_mfma_f32_16x16x32_bf16(af, b0, oa0, 0, 0, 0);
      oa1 = __builtin_amdgcn_mfma_f32_16x16x32_bf16(af, b1, oa1, 0, 0, 0);
    }
    __syncthreads();
  }
  // dump om (+bias): C layout col=l15 (oc), row=quad*4+reg (px in m-tile)
#pragma unroll
  for (int nt = 0; nt < 2; ++nt) {
    f32x4 a = nt ? oa1 : oa0;
    int oc = nt * 16 + l15;
    float bia = bias32[oc];
#pragma unroll
    for (int r = 0; r < 4; ++r)
      om[oc][w * 16 + quad * 4 + r] = a[r] + bia;
  }
  __syncthreads();

  // ===== phase 2: bilinear params -> sidxw =====
  for (int e = t; e < KK * 64; e += 256) {
    int tap = e >> 6, pp = e & 63;
    int gp2 = pblk + pp;
    int h = gp2 / WW, ww_ = gp2 % WW;
    float dy = om[2 * tap][pp], dx = om[2 * tap + 1][pp];
    float mr = om[18 + tap][pp];
    float m = 1.f / (1.f + __expf(-mr));
    float py  = (float)(h + tap / 3 - 1) + dy;
    float pxx = (float)(ww_ + tap % 3 - 1) + dx;
    float y0f = floorf(py), x0f = floorf(pxx);
    int y0 = (int)y0f, x0 = (int)x0f;
    float ly = py - y0f, lx = pxx - x0f;
    int y1 = y0 + 1, x1 = x0 + 1;
    bool vy0 = (unsigned)y0 < HH, vy1 = (unsigned)y1 < HH;
    bool vx0 = (unsigned)x0 < WW, vx1 = (unsigned)x1 < WW;
    int cy0 = min(max(y0, 0), HH - 1), cy1 = min(max(y1, 0), HH - 1);
    int cx0 = min(max(x0, 0), WW - 1), cx1 = min(max(x1, 0), WW - 1);
    unsigned i00 = cy0 * WW + cx0, i01 = cy0 * WW + cx1;
    unsigned i10 = cy1 * WW + cx0, i11 = cy1 * WW + cx1;
    float w00 = (vy0 && vx0) ? m * (1.f - ly) * (1.f - lx) : 0.f;
    float w01 = (vy0 && vx1) ? m * (1.f - ly) * lx         : 0.f;
    float w10 = (vy1 && vx0) ? m * ly * (1.f - lx)         : 0.f;
    float w11 = (vy1 && vx1) ? m * ly * lx                 : 0.f;
    sidxw[(tap * 4 + 0) * 64 + pp] = i00 | ((unsigned)f2bf(w00) << 16);
    sidxw[(tap * 4 + 1) * 64 + pp] = i01 | ((unsigned)f2bf(w01) << 16);
    sidxw[(tap * 4 + 2) * 64 + pp] = i10 | ((unsigned)f2bf(w10) << 16);
    sidxw[(tap * 4 + 3) * 64 + pp] = i11 | ((unsigned)f2bf(w11) << 16);
  }
  __syncthreads();

  // ===== phase 3: deformable GEMM =====
  f32x4 acc[8];
#pragma unroll
  for (int nt = 0; nt < 8; ++nt) acc[nt] = (f32x4){0.f, 0.f, 0.f, 0.f};
  const unsigned short* xnb = xn + ((size_t)b * HWSZ) * 128;

  for (int tap = 0; tap < KK; ++tap) {
    // per-corner idx|weight for this lane's 4 gather pixels
    unsigned sw[4][4];
#pragma unroll
    for (int cr = 0; cr < 4; ++cr)
#pragma unroll
      for (int G = 0; G < 4; ++G)
        sw[cr][G] = sidxw[(tap * 4 + cr) * 64 + w * 16 + G * 4 + quad];
    // gather: one instr = full 256B rows of 4 pixels' corner cr
    uint4 v[4][4];
#pragma unroll
    for (int G = 0; G < 4; ++G)
#pragma unroll
      for (int cr = 0; cr < 4; ++cr)
        v[cr][G] = *(const uint4*)(xnb + ((size_t)(sw[cr][G] & 0xffffu) << 7) + l15 * 8);
    // combine corners in-lane, write A tile
#pragma unroll
    for (int G = 0; G < 4; ++G) {
      float f[8];
#pragma unroll
      for (int j = 0; j < 8; ++j) f[j] = 0.f;
#pragma unroll
      for (int cr = 0; cr < 4; ++cr) {
        float wc = bf2f_hi(sw[cr][G]);
        const unsigned* a = (const unsigned*)&v[cr][G];
#pragma unroll
        for (int j = 0; j < 4; ++j) {
          f[2 * j]     += wc * bf2f_lo(a[j]);
          f[2 * j + 1] += wc * bf2f_hi(a[j]);
        }
      }
      unsigned od[4];
#pragma unroll
      for (int j = 0; j < 4; ++j) od[j] = pack_bf(f[2 * j], f[2 * j + 1]);
      *(uint4*)&val[w * 16 + G * 4 + quad][l15 * 8] =
          make_uint4(od[0], od[1], od[2], od[3]);
    }
    // stage B half 0 (o rows 0..63)
#pragma unroll
    for (int j = 0; j < 4; ++j) {
      int cc = t + 256 * j;
      int row = cc >> 4, c16 = cc & 15;
      *(uint4*)&bw[row * 68 + c16 * 4] =
          *(const uint4*)(wtb + (size_t)row * KTOT + tap * 128 + c16 * 8);
    }
    __syncthreads();
    bf16x8 af[4];
#pragma unroll
    for (int ks = 0; ks < 4; ++ks)
      af[ks] = *(const bf16x8*)&val[w * 16 + l15][ks * 32 + quad * 8];
#pragma unroll
    for (int ks = 0; ks < 4; ++ks)
#pragma unroll
      for (int nt = 0; nt < 4; ++nt) {
        bf16x8 bb = *(const bf16x8*)&bw[(size_t)(nt * 16 + l15) * 68 + ks * 16 + quad * 4];
        acc[nt] = __builtin_amdgcn_mfma_f32_16x16x32_bf16(af[ks], bb, acc[nt], 0, 0, 0);
      }
    __syncthreads();
    // stage B half 1 (o rows 64..127)
#pragma unroll
    for (int j = 0; j < 4; ++j) {
      int cc = t + 256 * j;
      int row = cc >> 4, c16 = cc & 15;
      *(uint4*)&bw[row * 68 + c16 * 4] =
          *(const uint4*)(wtb + (size_t)(64 + row) * KTOT + tap * 128 + c16 * 8);
    }
    __syncthreads();
#pragma unroll
    for (int ks = 0; ks < 4; ++ks)
#pragma unroll
      for (int nt = 0; nt < 4; ++nt) {
        bf16x8 bb = *(const bf16x8*)&bw[(size_t)(nt * 16 + l15) * 68 + ks * 16 + quad * 4];
        acc[4 + nt] = __builtin_amdgcn_mfma_f32_16x16x32_bf16(af[ks], bb, acc[4 + nt], 0, 0, 0);
      }
    __syncthreads();
  }

  // ===== phase 4: epilogue =====
  for (int r = 0; r < 4; ++r) {
    f32x4 a0 = acc[2 * r], a1 = acc[2 * r + 1];
    float db0 = defb[r * 32 + l15];
    float db1 = defb[r * 32 + 16 + l15];
    if (r) __syncthreads();
#pragma unroll
    for (int reg = 0; reg < 4; ++reg) {
      om[l15]     [w * 16 + quad * 4 + reg] = a0[reg] + db0;
      om[16 + l15][w * 16 + quad * 4 + reg] = a1[reg] + db1;
    }
    __syncthreads();
    int row = t >> 4;
    int col4 = (t & 15) * 4;
#pragma unroll
    for (int hrow = 0; hrow < 2; ++hrow) {
      int rr = row + hrow * 16;
      float4 vv = *(float4*)&om[rr][col4];
      *(float4*)&out[((size_t)b * OUTC + r * 32 + rr) * HWSZ + pblk + col4] = vv;
    }
  }
}

extern "C" void kernel_launch(void* const* d_in, const int* in_sizes, int n_in,
                              void* d_out, int out_size, void* d_ws, size_t ws_size,
                              hipStream_t stream) {
  const float* x     = (const float*)d_in[0];
  const float* x2    = (const float*)d_in[1];
  const float* offw  = (const float*)d_in[2];
  const float* offb  = (const float*)d_in[3];
  const float* maskw = (const float*)d_in[4];
  const float* maskb = (const float*)d_in[5];
  const float* defw  = (const float*)d_in[6];
  const float* defb  = (const float*)d_in[7];
  float* out = (float*)d_out;

  hipLaunchKernelGGL(prep_all, dim3(1873), dim3(256), 0, stream,
                     x, x2, offw, maskw, defw, offb, maskb, d_ws);
  hipLaunchKernelGGL(fused, dim3(576), dim3(256), 0, stream, defb, d_ws, out);
}